// Round 3
// baseline (402.070 us; speedup 1.0000x reference)
//
#include <hip/hip_runtime.h>

#define N_NODES 51200
#define N_EDGES 819200
#define HDIM 128
#define AK 256          // GEMM K = 2*HDIM (agg | x)
#define NGRAPH 128
#define SEG 400
#define NOUT 10
#define SLOT 64         // fixed col2 slot per node (deg ~ Poisson(16); P(>64) ~ 1e-13)

// counting-sort CSR build (replaces atomic scatter; atomics were the 56us floor)
#define HISTW (N_NODES / 4)   // 12800 words, 4 byte-bins per word (50 KB LDS)
#define NBLK 200              // edge partitions
#define EPB (N_EDGES / NBLK)  // 4096 edges per partition
#define SEGS 8
#define BPSEG (NBLK / SEGS)   // 25 partitions per scan segment

typedef unsigned short ushort_t;
typedef unsigned int uint_t;
typedef __attribute__((ext_vector_type(8))) short bf16x8;
typedef __attribute__((ext_vector_type(16))) float f32x16;

static __device__ __forceinline__ unsigned short f2bf(float f) {
    unsigned int u = __float_as_uint(f);
    unsigned int r = (u + 0x7fffu + ((u >> 16) & 1u)) >> 16;  // RNE
    return (unsigned short)r;
}
static __device__ __forceinline__ float bf2f(unsigned short h) {
    return __uint_as_float(((unsigned int)h) << 16);
}

// ---------------- prep: cast x0 -> Abuf right half, build Wfrags, zero pooled -------

__global__ void k_prep(const float* __restrict__ x, ushort_t* __restrict__ Abuf,
                       const float* __restrict__ W1rel, const float* __restrict__ W1root,
                       const float* __restrict__ W2rel, const float* __restrict__ W2root,
                       ushort_t* __restrict__ Wfrag1, ushort_t* __restrict__ Wfrag2,
                       float* __restrict__ pooled) {
    int b = blockIdx.x;
    if (b < 6400) {
        int idx = b * 256 + threadIdx.x;
        int row = idx >> 5;
        int c4 = (idx & 31) * 4;
        float4 v = *(const float4*)(x + (size_t)row * HDIM + c4);
        ushort4 h;
        h.x = f2bf(v.x); h.y = f2bf(v.y); h.z = f2bf(v.z); h.w = f2bf(v.w);
        *(ushort4*)(Abuf + (size_t)row * AK + HDIM + c4) = h;
    } else if (b < 6656) {
        int w2 = (b >= 6528);
        int tid = (b - (w2 ? 6528 : 6400)) * 256 + threadIdx.x;  // 0..32767
        const float* Wrel  = w2 ? W2rel : W1rel;
        const float* Wroot = w2 ? W2root : W1root;
        ushort_t* dstF     = w2 ? Wfrag2 : Wfrag1;
        int j = tid & 7;
        int l = (tid >> 3) & 63;
        int s = (tid >> 9) & 15;
        int t = tid >> 13;
        int k = 16 * s + (l >> 5) * 8 + j;
        int n = 32 * t + (l & 31);
        float v = (k < HDIM) ? Wrel[(size_t)k * HDIM + n]
                             : Wroot[(size_t)(k - HDIM) * HDIM + n];
        dstF[tid] = f2bf(v);
    } else {
        int i = (b - 6656) * 256 + threadIdx.x;  // 0..16383
        pooled[i] = 0.f;
    }
}

// ---------------- CSR pass 1: per-partition byte histogram (LDS atomics only) -------

__global__ __launch_bounds__(256) void k_count(const int* __restrict__ dst,
                                               uint_t* __restrict__ bh) {
    __shared__ uint_t hist[HISTW];
    int b = blockIdx.x, tid = threadIdx.x;
    for (int i = tid; i < HISTW; i += 256) hist[i] = 0u;
    __syncthreads();
    const int4* d4 = (const int4*)dst + b * (EPB / 4);
#pragma unroll
    for (int p = 0; p < 4; ++p) {
        int4 d = d4[p * 256 + tid];
        atomicAdd(&hist[((uint_t)d.x) >> 2], 1u << ((d.x & 3) * 8));
        atomicAdd(&hist[((uint_t)d.y) >> 2], 1u << ((d.y & 3) * 8));
        atomicAdd(&hist[((uint_t)d.z) >> 2], 1u << ((d.z & 3) * 8));
        atomicAdd(&hist[((uint_t)d.w) >> 2], 1u << ((d.w & 3) * 8));
    }
    __syncthreads();
    for (int i = tid; i < HISTW; i += 256) bh[(size_t)b * HISTW + i] = hist[i];
}

// ---------------- CSR pass 2: in-place SWAR exclusive scan over partitions ----------
// Byte lanes never carry: per-node total degree <= ~50 < 256. Seg-7 total == cnt.

__global__ __launch_bounds__(256) void k_prefix(uint_t* __restrict__ bh,
                                                int* __restrict__ cnt) {
    __shared__ uint_t segsum[SEGS][32];
    int ci = threadIdx.x & 31;
    int seg = threadIdx.x >> 5;
    int c = blockIdx.x * 32 + ci;
    uint_t v[BPSEG];
    uint_t sum = 0;
#pragma unroll
    for (int k = 0; k < BPSEG; ++k) {
        v[k] = bh[(size_t)(seg * BPSEG + k) * HISTW + c];
        sum += v[k];
    }
    segsum[seg][ci] = sum;
    __syncthreads();
    uint_t run = 0;
    for (int s = 0; s < seg; ++s) run += segsum[s][ci];
#pragma unroll
    for (int k = 0; k < BPSEG; ++k) {
        bh[(size_t)(seg * BPSEG + k) * HISTW + c] = run;
        run += v[k];
    }
    if (seg == SEGS - 1) {
        int4 o;
        o.x = (int)(run & 0xffu);
        o.y = (int)((run >> 8) & 0xffu);
        o.z = (int)((run >> 16) & 0xffu);
        o.w = (int)((run >> 24) & 0xffu);
        *(int4*)(cnt + 4 * c) = o;
    }
}

// ---------------- CSR pass 3: place edges; LDS atomic returns final slot ------------

__global__ __launch_bounds__(256) void k_place(const int* __restrict__ src,
                                               const int* __restrict__ dst,
                                               const uint_t* __restrict__ bh,
                                               ushort_t* __restrict__ col2) {
    __shared__ uint_t hist[HISTW];
    int b = blockIdx.x, tid = threadIdx.x;
    for (int i = tid; i < HISTW; i += 256) hist[i] = bh[(size_t)b * HISTW + i];
    __syncthreads();
    const int4* d4 = (const int4*)dst + b * (EPB / 4);
    const int4* s4 = (const int4*)src + b * (EPB / 4);
#pragma unroll
    for (int p = 0; p < 4; ++p) {
        int4 d = d4[p * 256 + tid];
        int4 s = s4[p * 256 + tid];
#define PLACE1(dd, ss)                                                        \
        do {                                                                  \
            uint_t w = (uint_t)(dd);                                          \
            int sh = (int)(w & 3u) * 8;                                       \
            uint_t old = atomicAdd(&hist[w >> 2], 1u << sh);                  \
            col2[(size_t)w * SLOT + ((old >> sh) & 0xffu)] = (ushort_t)(ss);  \
        } while (0)
        PLACE1(d.x, s.x);
        PLACE1(d.y, s.y);
        PLACE1(d.z, s.z);
        PLACE1(d.w, s.w);
#undef PLACE1
    }
}

// ---------------- aggregation: quarter-column passes, L2-resident working set -------
// agg[dst][c] is column-independent -> split HDIM into 4 x 64B quarters. One
// quarter's gather working set = 51200 x 64B = 3.25 MB < 4 MB per-XCD L2, so
// quarter-major dispatch turns the random row-gathers into L2 hits (was ~60%
// miss at 256B rows / 13 MB working set, FETCH 83.6 MB/layer). Wave = one
// (node, quarter): 16 edges in flight, 16B/lane, zero LDS, full occupancy.

__global__ __launch_bounds__(256) void k_aggq(ushort_t* __restrict__ Abuf,
                                              const int* __restrict__ cnt,
                                              const ushort_t* __restrict__ col) {
    int wv = threadIdx.x >> 6;
    int lane = threadIdx.x & 63;
    int il = lane & 3;           // 16B sub-chunk within the 64B quarter
    int qe = lane >> 2;          // edge within group of 16
    int q = blockIdx.x / (N_NODES / 4);            // quarter (quarter-major grid)
    int node = (blockIdx.x % (N_NODES / 4)) * 4 + wv;
    int beg = node * SLOT;
    int end = beg + cnt[node];

    const ushort_t* xsrc = Abuf + HDIM + q * 32 + (size_t)il * 8;

    float a[8];
#pragma unroll
    for (int k = 0; k < 8; ++k) a[k] = 0.f;

    int e = beg;
    for (; e + 16 <= end; e += 16) {
        int c = (int)col[e + qe];
        uint4 v = *(const uint4*)(xsrc + (size_t)c * AK);
        a[0] += __uint_as_float(v.x << 16);
        a[1] += __uint_as_float(v.x & 0xffff0000u);
        a[2] += __uint_as_float(v.y << 16);
        a[3] += __uint_as_float(v.y & 0xffff0000u);
        a[4] += __uint_as_float(v.z << 16);
        a[5] += __uint_as_float(v.z & 0xffff0000u);
        a[6] += __uint_as_float(v.w << 16);
        a[7] += __uint_as_float(v.w & 0xffff0000u);
    }
    if (e < end) {
        int idx = e + qe;
        bool ok = idx < end;
        int c = (int)col[ok ? idx : e];
        uint4 v = *(const uint4*)(xsrc + (size_t)c * AK);
        a[0] += ok ? __uint_as_float(v.x << 16) : 0.f;
        a[1] += ok ? __uint_as_float(v.x & 0xffff0000u) : 0.f;
        a[2] += ok ? __uint_as_float(v.y << 16) : 0.f;
        a[3] += ok ? __uint_as_float(v.y & 0xffff0000u) : 0.f;
        a[4] += ok ? __uint_as_float(v.z << 16) : 0.f;
        a[5] += ok ? __uint_as_float(v.z & 0xffff0000u) : 0.f;
        a[6] += ok ? __uint_as_float(v.w << 16) : 0.f;
        a[7] += ok ? __uint_as_float(v.w & 0xffff0000u) : 0.f;
    }

    // reduce across the 16 edge-groups (lane bits 2..5); all lanes execute
#pragma unroll
    for (int k = 0; k < 8; ++k) {
        a[k] += __shfl_xor(a[k], 4);
        a[k] += __shfl_xor(a[k], 8);
        a[k] += __shfl_xor(a[k], 16);
        a[k] += __shfl_xor(a[k], 32);
    }

    if (qe == 0) {
        uint4 o;
        o.x = (uint_t)f2bf(a[0]) | ((uint_t)f2bf(a[1]) << 16);
        o.y = (uint_t)f2bf(a[2]) | ((uint_t)f2bf(a[3]) << 16);
        o.z = (uint_t)f2bf(a[4]) | ((uint_t)f2bf(a[5]) << 16);
        o.w = (uint_t)f2bf(a[6]) | ((uint_t)f2bf(a[7]) << 16);
        *(uint4*)(Abuf + (size_t)node * AK + q * 32 + il * 8) = o;
    }
}

// ---------------- MFMA GEMM (layers 1-2): split-N, wave = 32 rows x 64 cols ---------

__global__ __launch_bounds__(64) void k_gemm_mfma(const ushort_t* __restrict__ Abuf,
                                                  const ushort_t* __restrict__ Wfrag,
                                                  const float* __restrict__ bias,
                                                  ushort_t* __restrict__ y) {
    __shared__ ushort_t sm[32][72];
    int lane = threadIdx.x;
    int nh = blockIdx.x & 1;
    int row0 = (blockIdx.x >> 1) * 32;
    int m = lane & 31;
    int half = lane >> 5;

    f32x16 acc[2];
#pragma unroll
    for (int t = 0; t < 2; ++t) acc[t] = (f32x16)(0.f);

    float bb[2];
#pragma unroll
    for (int t = 0; t < 2; ++t) bb[t] = bias[nh * 64 + t * 32 + m];

    const ushort_t* arow = Abuf + (size_t)(row0 + m) * AK + half * 8;
    const ushort_t* wf = Wfrag + (size_t)lane * 8 + (size_t)nh * 2 * 16 * 512;

#pragma unroll
    for (int s = 0; s < 16; ++s) {
        bf16x8 afrag = *(const bf16x8*)(arow + s * 16);
#pragma unroll
        for (int t = 0; t < 2; ++t) {
            bf16x8 bfrag = *(const bf16x8*)(wf + (size_t)(t * 16 + s) * 512);
            acc[t] = __builtin_amdgcn_mfma_f32_32x32x16_bf16(afrag, bfrag, acc[t], 0, 0, 0);
        }
    }

#pragma unroll
    for (int t = 0; t < 2; ++t) {
#pragma unroll
        for (int r = 0; r < 16; ++r) {
            int rowL = (r & 3) + 8 * (r >> 2) + 4 * half;
            sm[rowL][t * 32 + m] = f2bf(fmaxf(acc[t][r] + bb[t], 0.f));
        }
    }
    __syncthreads();
    int seg = lane & 7;
    int rbase = lane >> 3;
#pragma unroll
    for (int it = 0; it < 4; ++it) {
        int rowL = rbase + it * 8;
        int4 chunk = *(const int4*)&sm[rowL][seg * 8];
        *(int4*)(y + (size_t)(row0 + rowL) * HDIM + nh * 64 + seg * 8) = chunk;
    }
}

// ---------------- MFMA GEMM layer-3: split-N, relu -> per-graph pooled atomicAdd -----

__global__ __launch_bounds__(64) void k_gemm_pool(const ushort_t* __restrict__ Abuf,
                                                  const ushort_t* __restrict__ Wfrag,
                                                  const float* __restrict__ bias,
                                                  float* __restrict__ pooled) {
    int lane = threadIdx.x;
    int nh = blockIdx.x & 1;
    int row0 = (blockIdx.x >> 1) * 32;
    int m = lane & 31;
    int half = lane >> 5;

    f32x16 acc[2];
#pragma unroll
    for (int t = 0; t < 2; ++t) acc[t] = (f32x16)(0.f);

    float bb[2];
#pragma unroll
    for (int t = 0; t < 2; ++t) bb[t] = bias[nh * 64 + t * 32 + m];

    const ushort_t* arow = Abuf + (size_t)(row0 + m) * AK + half * 8;
    const ushort_t* wf = Wfrag + (size_t)lane * 8 + (size_t)nh * 2 * 16 * 512;

#pragma unroll
    for (int s = 0; s < 16; ++s) {
        bf16x8 afrag = *(const bf16x8*)(arow + s * 16);
#pragma unroll
        for (int t = 0; t < 2; ++t) {
            bf16x8 bfrag = *(const bf16x8*)(wf + (size_t)(t * 16 + s) * 512);
            acc[t] = __builtin_amdgcn_mfma_f32_32x32x16_bf16(afrag, bfrag, acc[t], 0, 0, 0);
        }
    }

    int g0 = row0 / SEG;
    int bnd = (g0 + 1) * SEG;
    int straddle = (row0 + 31 >= bnd);

#pragma unroll
    for (int t = 0; t < 2; ++t) {
        float s0 = 0.f, s1 = 0.f;
#pragma unroll
        for (int r = 0; r < 16; ++r) {
            int row = row0 + (r & 3) + 8 * (r >> 2) + 4 * half;
            float v = fmaxf(acc[t][r] + bb[t], 0.f);
            if (row < bnd) s0 += v; else s1 += v;
        }
        s0 += __shfl_xor(s0, 32);
        s1 += __shfl_xor(s1, 32);
        if (half == 0) {
            int coln = nh * 64 + t * 32 + m;
            atomicAdd(&pooled[g0 * HDIM + coln], s0);
            if (straddle) atomicAdd(&pooled[(g0 + 1) * HDIM + coln], s1);
        }
    }
}

// ---------------- mixup: bf16 y -> Abuf right half ----------------

__global__ void k_mixup_toA(const ushort_t* __restrict__ y, const int* __restrict__ perm,
                            const float* __restrict__ lam, ushort_t* __restrict__ Abuf) {
    int idx = blockIdx.x * 256 + threadIdx.x;
    int row = idx >> 5;
    int c4 = (idx & 31) * 4;
    float l = lam[0];
    float om = 1.f - l;
    int p = perm[row];
    ushort4 a = *(const ushort4*)(y + (size_t)row * HDIM + c4);
    ushort4 b = *(const ushort4*)(y + (size_t)p * HDIM + c4);
    ushort4 o;
    o.x = f2bf(l * bf2f(a.x) + om * bf2f(b.x));
    o.y = f2bf(l * bf2f(a.y) + om * bf2f(b.y));
    o.z = f2bf(l * bf2f(a.z) + om * bf2f(b.z));
    o.w = f2bf(l * bf2f(a.w) + om * bf2f(b.w));
    *(ushort4*)(Abuf + (size_t)row * AK + HDIM + c4) = o;
}

// ---------------- final: linear + log_softmax from pooled ----------------

__global__ __launch_bounds__(64) void k_final(const float* __restrict__ pooled,
                                              const float* __restrict__ Wlin,
                                              const float* __restrict__ blin,
                                              float* __restrict__ out) {
    int g = blockIdx.x;
    int lane = threadIdx.x;
    float2 v = *(const float2*)(pooled + (size_t)g * HDIM + lane * 2);
    float p[NOUT];
#pragma unroll
    for (int o = 0; o < NOUT; ++o)
        p[o] = v.x * Wlin[(size_t)(2 * lane) * NOUT + o] +
               v.y * Wlin[(size_t)(2 * lane + 1) * NOUT + o];
#pragma unroll
    for (int mask = 1; mask < 64; mask <<= 1)
#pragma unroll
        for (int o = 0; o < NOUT; ++o) p[o] += __shfl_xor(p[o], mask);
    if (lane == 0) {
        float lg[NOUT];
        float mx = -1e30f;
#pragma unroll
        for (int o = 0; o < NOUT; ++o) { lg[o] = p[o] + blin[o]; mx = fmaxf(mx, lg[o]); }
        float se = 0.f;
#pragma unroll
        for (int o = 0; o < NOUT; ++o) se += expf(lg[o] - mx);
        float lse = mx + logf(se);
#pragma unroll
        for (int o = 0; o < NOUT; ++o) out[g * NOUT + o] = lg[o] - lse;
    }
}

// ---------------- host ----------------

extern "C" void kernel_launch(void* const* d_in, const int* in_sizes, int n_in,
                              void* d_out, int out_size, void* d_ws, size_t ws_size,
                              hipStream_t stream) {
    const float* x0     = (const float*)d_in[0];
    const int*   edge   = (const int*)d_in[1];
    const int*   src    = edge;
    const int*   dst    = edge + N_EDGES;
    const float* lam    = (const float*)d_in[2];
    const int*   perm1  = (const int*)d_in[5];
    const int*   perm2  = (const int*)d_in[6];
    const float* W1_rel = (const float*)d_in[8];
    const float* b1_rel = (const float*)d_in[9];
    const float* W1_root= (const float*)d_in[10];
    const float* W2_rel = (const float*)d_in[11];
    const float* b2_rel = (const float*)d_in[12];
    const float* W2_root= (const float*)d_in[13];
    const float* W_lin  = (const float*)d_in[14];
    const float* b_lin  = (const float*)d_in[15];
    float* out = (float*)d_out;

    char* w = (char*)d_ws;
    size_t off = 0;
    auto alloc = [&](size_t bytes) -> void* {
        void* p = w + off;
        off = (off + bytes + 255) & ~(size_t)255;
        return p;
    };
    int* cnt       = (int*)alloc((size_t)N_NODES * 4);
    ushort_t* col2 = (ushort_t*)alloc((size_t)N_NODES * SLOT * 2);
    ushort_t* Abuf   = (ushort_t*)alloc((size_t)N_NODES * AK * 2);
    ushort_t* ybuf   = (ushort_t*)alloc((size_t)N_NODES * HDIM * 2);
    ushort_t* Wfrag1 = (ushort_t*)alloc(32768 * 2);
    ushort_t* Wfrag2 = (ushort_t*)alloc(32768 * 2);
    float* pooled    = (float*)alloc((size_t)NGRAPH * HDIM * 4);

    // block-histogram matrix aliases ybuf (10.24 MB <= 13.1 MB): ybuf is dead
    // until the layer-1 GEMM writes it, strictly after k_place completes.
    uint_t* bh = (uint_t*)ybuf;

    // prep (casts x0 -> Abuf right half, builds Wfrags, zeroes pooled)
    k_prep<<<6720, 256, 0, stream>>>(x0, Abuf, W1_rel, W1_root, W2_rel, W2_root,
                                     Wfrag1, Wfrag2, pooled);
    // CSR build: atomic-free counting sort (LDS byte-histograms)
    k_count<<<NBLK, 256, 0, stream>>>(dst, bh);
    k_prefix<<<HISTW / 32, 256, 0, stream>>>(bh, cnt);
    k_place<<<NBLK, 256, 0, stream>>>(src, dst, bh, col2);

    const int aggGrid  = N_NODES;                    // 4 quarters x 12800 blocks
    const int gemmGrid = (N_NODES / 32) * 2;
    const int elGrid   = (N_NODES * HDIM / 4) / 256;

    // layer 1
    k_aggq<<<aggGrid, 256, 0, stream>>>(Abuf, cnt, col2);
    k_gemm_mfma<<<gemmGrid, 64, 0, stream>>>(Abuf, Wfrag1, b1_rel, ybuf);
    k_mixup_toA<<<elGrid, 256, 0, stream>>>(ybuf, perm1, lam, Abuf);
    // layer 2
    k_aggq<<<aggGrid, 256, 0, stream>>>(Abuf, cnt, col2);
    k_gemm_mfma<<<gemmGrid, 64, 0, stream>>>(Abuf, Wfrag2, b2_rel, ybuf);
    k_mixup_toA<<<elGrid, 256, 0, stream>>>(ybuf, perm2, lam, Abuf);
    // layer 3 (mixup3 is a pooling no-op -> fused pool)
    k_aggq<<<aggGrid, 256, 0, stream>>>(Abuf, cnt, col2);
    k_gemm_pool<<<gemmGrid, 64, 0, stream>>>(Abuf, Wfrag2, b2_rel, pooled);

    // classifier + log_softmax
    k_final<<<NGRAPH, 64, 0, stream>>>(pooled, W_lin, b_lin, out);
}

// Round 4
// 264.285 us; speedup vs baseline: 1.5214x; 1.5214x over previous
//
#include <hip/hip_runtime.h>

#define N_NODES 51200
#define N_EDGES 819200
#define HDIM 128
#define AK 256          // GEMM K = 2*HDIM (agg | x)
#define NGRAPH 128
#define SEG 400
#define NOUT 10
#define SLOT 64         // fixed col2 slot per node (deg ~ Poisson(16); P(>64) ~ 1e-13)

// counting-sort CSR build (replaces atomic scatter; atomics were the 56us floor)
#define HISTW (N_NODES / 4)   // 12800 words, 4 byte-bins per word (50 KB LDS)
#define NBLK 200              // edge partitions
#define EPB (N_EDGES / NBLK)  // 4096 edges per partition
#define SEGS 8
#define BPSEG (NBLK / SEGS)   // 25 partitions per scan segment

#define LDSW 264              // GEMM A-tile ushort stride (16B-aligned rows)

typedef unsigned short ushort_t;
typedef unsigned int uint_t;
typedef __attribute__((ext_vector_type(8))) short bf16x8;
typedef __attribute__((ext_vector_type(16))) float f32x16;

static __device__ __forceinline__ unsigned short f2bf(float f) {
    unsigned int u = __float_as_uint(f);
    unsigned int r = (u + 0x7fffu + ((u >> 16) & 1u)) >> 16;  // RNE
    return (unsigned short)r;
}
static __device__ __forceinline__ float bf2f(unsigned short h) {
    return __uint_as_float(((unsigned int)h) << 16);
}

// ------- prep+count: CSR histogram (first, overlaps), cast x0, Wfrags, pooled -------
// blocks: 0..199 count | 200..6599 cast | 6600..6727 wf1 | 6728..6855 wf2 | 6856..6919 pooled

__global__ void k_prep(const float* __restrict__ x, ushort_t* __restrict__ Abuf,
                       const float* __restrict__ W1rel, const float* __restrict__ W1root,
                       const float* __restrict__ W2rel, const float* __restrict__ W2root,
                       ushort_t* __restrict__ Wfrag1, ushort_t* __restrict__ Wfrag2,
                       float* __restrict__ pooled, const int* __restrict__ dst,
                       uint_t* __restrict__ bh) {
    __shared__ uint_t hist[HISTW];
    int b = blockIdx.x;
    int tid = threadIdx.x;
    if (b < NBLK) {
        // ---- CSR pass 1: per-partition byte histogram (LDS atomics only) ----
        for (int i = tid; i < HISTW; i += 256) hist[i] = 0u;
        __syncthreads();
        const int4* d4 = (const int4*)dst + b * (EPB / 4);
#pragma unroll
        for (int p = 0; p < 4; ++p) {
            int4 d = d4[p * 256 + tid];
            atomicAdd(&hist[((uint_t)d.x) >> 2], 1u << ((d.x & 3) * 8));
            atomicAdd(&hist[((uint_t)d.y) >> 2], 1u << ((d.y & 3) * 8));
            atomicAdd(&hist[((uint_t)d.z) >> 2], 1u << ((d.z & 3) * 8));
            atomicAdd(&hist[((uint_t)d.w) >> 2], 1u << ((d.w & 3) * 8));
        }
        __syncthreads();
        for (int i = tid; i < HISTW; i += 256) bh[(size_t)b * HISTW + i] = hist[i];
    } else if (b < 6600) {
        int idx = (b - NBLK) * 256 + tid;
        int row = idx >> 5;
        int c4 = (idx & 31) * 4;
        float4 v = *(const float4*)(x + (size_t)row * HDIM + c4);
        ushort4 h;
        h.x = f2bf(v.x); h.y = f2bf(v.y); h.z = f2bf(v.z); h.w = f2bf(v.w);
        *(ushort4*)(Abuf + (size_t)row * AK + HDIM + c4) = h;
    } else if (b < 6856) {
        int w2 = (b >= 6728);
        int t0 = (b - (w2 ? 6728 : 6600)) * 256 + tid;  // 0..32767
        const float* Wrel  = w2 ? W2rel : W1rel;
        const float* Wroot = w2 ? W2root : W1root;
        ushort_t* dstF     = w2 ? Wfrag2 : Wfrag1;
        int j = t0 & 7;
        int l = (t0 >> 3) & 63;
        int s = (t0 >> 9) & 15;
        int t = t0 >> 13;
        int k = 16 * s + (l >> 5) * 8 + j;
        int n = 32 * t + (l & 31);
        float v = (k < HDIM) ? Wrel[(size_t)k * HDIM + n]
                             : Wroot[(size_t)(k - HDIM) * HDIM + n];
        dstF[t0] = f2bf(v);
    } else {
        int i = (b - 6856) * 256 + tid;  // 0..16383
        pooled[i] = 0.f;
    }
}

// ---------------- CSR pass 2: in-place SWAR exclusive scan over partitions ----------
// Byte lanes never carry: per-node total degree <= ~50 < 256. Seg-7 total == cnt.

__global__ __launch_bounds__(256) void k_prefix(uint_t* __restrict__ bh,
                                                int* __restrict__ cnt) {
    __shared__ uint_t segsum[SEGS][32];
    int ci = threadIdx.x & 31;
    int seg = threadIdx.x >> 5;
    int c = blockIdx.x * 32 + ci;
    uint_t v[BPSEG];
    uint_t sum = 0;
#pragma unroll
    for (int k = 0; k < BPSEG; ++k) {
        v[k] = bh[(size_t)(seg * BPSEG + k) * HISTW + c];
        sum += v[k];
    }
    segsum[seg][ci] = sum;
    __syncthreads();
    uint_t run = 0;
    for (int s = 0; s < seg; ++s) run += segsum[s][ci];
#pragma unroll
    for (int k = 0; k < BPSEG; ++k) {
        bh[(size_t)(seg * BPSEG + k) * HISTW + c] = run;
        run += v[k];
    }
    if (seg == SEGS - 1) {
        int4 o;
        o.x = (int)(run & 0xffu);
        o.y = (int)((run >> 8) & 0xffu);
        o.z = (int)((run >> 16) & 0xffu);
        o.w = (int)((run >> 24) & 0xffu);
        *(int4*)(cnt + 4 * c) = o;
    }
}

// ---------------- CSR pass 3: place edges; LDS atomic returns final slot ------------

__global__ __launch_bounds__(256) void k_place(const int* __restrict__ src,
                                               const int* __restrict__ dst,
                                               const uint_t* __restrict__ bh,
                                               ushort_t* __restrict__ col2) {
    __shared__ uint_t hist[HISTW];
    int b = blockIdx.x, tid = threadIdx.x;
    for (int i = tid; i < HISTW; i += 256) hist[i] = bh[(size_t)b * HISTW + i];
    __syncthreads();
    const int4* d4 = (const int4*)dst + b * (EPB / 4);
    const int4* s4 = (const int4*)src + b * (EPB / 4);
#pragma unroll
    for (int p = 0; p < 4; ++p) {
        int4 d = d4[p * 256 + tid];
        int4 s = s4[p * 256 + tid];
#define PLACE1(dd, ss)                                                        \
        do {                                                                  \
            uint_t w = (uint_t)(dd);                                          \
            int sh = (int)(w & 3u) * 8;                                       \
            uint_t old = atomicAdd(&hist[w >> 2], 1u << sh);                  \
            col2[(size_t)w * SLOT + ((old >> sh) & 0xffu)] = (ushort_t)(ss);  \
        } while (0)
        PLACE1(d.x, s.x);
        PLACE1(d.y, s.y);
        PLACE1(d.z, s.z);
        PLACE1(d.w, s.w);
#undef PLACE1
    }
}

// ---------------- aggregation: quad-edge 16B gathers (R13, proven <42us) ----------

__global__ __launch_bounds__(256) void k_aggregate(ushort_t* __restrict__ Abuf,
                                                   const int* __restrict__ cnt,
                                                   const ushort_t* __restrict__ col) {
    int wave = threadIdx.x >> 6;
    int lane = threadIdx.x & 63;
    int il = lane & 15;          // col group: cols 8*il..8*il+7 (16 B)
    int qe = lane >> 4;          // edge within quad: 0..3
    int node = blockIdx.x * 4 + wave;
    int beg = node * SLOT;
    int end = beg + cnt[node];

    const ushort_t* xsrc = Abuf + HDIM + (size_t)il * 8;

    float a[4][8];
#pragma unroll
    for (int j = 0; j < 4; ++j)
#pragma unroll
        for (int k = 0; k < 8; ++k) a[j][k] = 0.f;

    int e = beg;
    for (; e + 16 <= end; e += 16) {
        int c[4];
#pragma unroll
        for (int j = 0; j < 4; ++j) c[j] = (int)col[e + 4 * j + qe];
#pragma unroll
        for (int j = 0; j < 4; ++j) {
            uint4 v = *(const uint4*)(xsrc + (size_t)c[j] * AK);
            a[j][0] += __uint_as_float(v.x << 16);
            a[j][1] += __uint_as_float(v.x & 0xffff0000u);
            a[j][2] += __uint_as_float(v.y << 16);
            a[j][3] += __uint_as_float(v.y & 0xffff0000u);
            a[j][4] += __uint_as_float(v.z << 16);
            a[j][5] += __uint_as_float(v.z & 0xffff0000u);
            a[j][6] += __uint_as_float(v.w << 16);
            a[j][7] += __uint_as_float(v.w & 0xffff0000u);
        }
    }
    for (; e + 4 <= end; e += 4) {
        int c = (int)col[e + qe];
        uint4 v = *(const uint4*)(xsrc + (size_t)c * AK);
        a[0][0] += __uint_as_float(v.x << 16);
        a[0][1] += __uint_as_float(v.x & 0xffff0000u);
        a[0][2] += __uint_as_float(v.y << 16);
        a[0][3] += __uint_as_float(v.y & 0xffff0000u);
        a[0][4] += __uint_as_float(v.z << 16);
        a[0][5] += __uint_as_float(v.z & 0xffff0000u);
        a[0][6] += __uint_as_float(v.w << 16);
        a[0][7] += __uint_as_float(v.w & 0xffff0000u);
    }
    if (e < end) {
        int idx = e + qe;
        bool ok = idx < end;
        int c = (int)col[ok ? idx : e];
        uint4 v = *(const uint4*)(xsrc + (size_t)c * AK);
        a[1][0] += ok ? __uint_as_float(v.x << 16) : 0.f;
        a[1][1] += ok ? __uint_as_float(v.x & 0xffff0000u) : 0.f;
        a[1][2] += ok ? __uint_as_float(v.y << 16) : 0.f;
        a[1][3] += ok ? __uint_as_float(v.y & 0xffff0000u) : 0.f;
        a[1][4] += ok ? __uint_as_float(v.z << 16) : 0.f;
        a[1][5] += ok ? __uint_as_float(v.z & 0xffff0000u) : 0.f;
        a[1][6] += ok ? __uint_as_float(v.w << 16) : 0.f;
        a[1][7] += ok ? __uint_as_float(v.w & 0xffff0000u) : 0.f;
    }

    float s[8];
#pragma unroll
    for (int k = 0; k < 8; ++k) {
        s[k] = (a[0][k] + a[1][k]) + (a[2][k] + a[3][k]);
        s[k] += __shfl_xor(s[k], 16);   // all lanes execute (R10 bpermute rule)
        s[k] += __shfl_xor(s[k], 32);
    }

    if (qe == 0) {
        uint4 o;
        o.x = (uint_t)f2bf(s[0]) | ((uint_t)f2bf(s[1]) << 16);
        o.y = (uint_t)f2bf(s[2]) | ((uint_t)f2bf(s[3]) << 16);
        o.z = (uint_t)f2bf(s[4]) | ((uint_t)f2bf(s[5]) << 16);
        o.w = (uint_t)f2bf(s[6]) | ((uint_t)f2bf(s[7]) << 16);
        *(uint4*)(Abuf + (size_t)node * AK + il * 8) = o;
    }
}

// -------- single-pass MFMA GEMM: 256-thr block = 32 rows x full N=128 (A read once) --
// LDS-stage the 32x256 A-tile (16 KB), wave w computes cols w*32..w*32+31.
// Old split-N read A twice (nh pair lands on different XCDs -> both fetch): -26 MB/layer.

template<int POOL>
__global__ __launch_bounds__(256) void k_gemm256(const ushort_t* __restrict__ Abuf,
                                                 const ushort_t* __restrict__ Wfrag,
                                                 const float* __restrict__ bias,
                                                 ushort_t* __restrict__ y,
                                                 float* __restrict__ pooled) {
    __shared__ ushort_t At[32][LDSW];
    int tid = threadIdx.x;
    int w = tid >> 6;
    int lane = tid & 63;
    int row0 = blockIdx.x * 32;

    // stage A-tile: 32 rows x 512 B, coalesced (wave covers 1 KB contiguous)
#pragma unroll
    for (int it = 0; it < 4; ++it) {
        int idx = it * 256 + tid;     // 0..1023
        int r = idx >> 5;
        int c16 = idx & 31;
        *(uint4*)&At[r][c16 * 8] = *(const uint4*)(Abuf + (size_t)(row0 + r) * AK + c16 * 8);
    }
    __syncthreads();

    int m = lane & 31;
    int half = lane >> 5;
    f32x16 acc = (f32x16)(0.f);
    float bb = bias[w * 32 + m];
    const ushort_t* arow = &At[m][half * 8];
    const ushort_t* wf = Wfrag + (size_t)lane * 8;

#pragma unroll
    for (int s = 0; s < 16; ++s) {
        bf16x8 afrag = *(const bf16x8*)(arow + s * 16);
        bf16x8 bfrag = *(const bf16x8*)(wf + (size_t)(w * 16 + s) * 512);
        acc = __builtin_amdgcn_mfma_f32_32x32x16_bf16(afrag, bfrag, acc, 0, 0, 0);
    }

    if (POOL == 0) {
        __syncthreads();   // all waves done reading At; reuse it for the y transpose
#pragma unroll
        for (int r = 0; r < 16; ++r) {
            int rowL = (r & 3) + 8 * (r >> 2) + 4 * half;
            At[rowL][w * 32 + m] = f2bf(fmaxf(acc[r] + bb, 0.f));
        }
        __syncthreads();
#pragma unroll
        for (int it = 0; it < 2; ++it) {
            int c = it * 256 + tid;
            int row = c >> 4;
            int sg = c & 15;
            *(int4*)(y + (size_t)(row0 + row) * HDIM + sg * 8) = *(const int4*)&At[row][sg * 8];
        }
    } else {
        int g0 = row0 / SEG;
        int bnd = (g0 + 1) * SEG;
        int straddle = (row0 + 31 >= bnd);
        float s0 = 0.f, s1 = 0.f;
#pragma unroll
        for (int r = 0; r < 16; ++r) {
            int row = row0 + (r & 3) + 8 * (r >> 2) + 4 * half;
            float v = fmaxf(acc[r] + bb, 0.f);
            if (row < bnd) s0 += v; else s1 += v;
        }
        s0 += __shfl_xor(s0, 32);
        s1 += __shfl_xor(s1, 32);
        if (half == 0) {
            int coln = w * 32 + m;
            atomicAdd(&pooled[g0 * HDIM + coln], s0);
            if (straddle) atomicAdd(&pooled[(g0 + 1) * HDIM + coln], s1);
        }
    }
}

// ---------------- mixup: bf16 y -> Abuf right half ----------------

__global__ void k_mixup_toA(const ushort_t* __restrict__ y, const int* __restrict__ perm,
                            const float* __restrict__ lam, ushort_t* __restrict__ Abuf) {
    int idx = blockIdx.x * 256 + threadIdx.x;
    int row = idx >> 5;
    int c4 = (idx & 31) * 4;
    float l = lam[0];
    float om = 1.f - l;
    int p = perm[row];
    ushort4 a = *(const ushort4*)(y + (size_t)row * HDIM + c4);
    ushort4 b = *(const ushort4*)(y + (size_t)p * HDIM + c4);
    ushort4 o;
    o.x = f2bf(l * bf2f(a.x) + om * bf2f(b.x));
    o.y = f2bf(l * bf2f(a.y) + om * bf2f(b.y));
    o.z = f2bf(l * bf2f(a.z) + om * bf2f(b.z));
    o.w = f2bf(l * bf2f(a.w) + om * bf2f(b.w));
    *(ushort4*)(Abuf + (size_t)row * AK + HDIM + c4) = o;
}

// ---------------- final: linear + log_softmax from pooled ----------------

__global__ __launch_bounds__(64) void k_final(const float* __restrict__ pooled,
                                              const float* __restrict__ Wlin,
                                              const float* __restrict__ blin,
                                              float* __restrict__ out) {
    int g = blockIdx.x;
    int lane = threadIdx.x;
    float2 v = *(const float2*)(pooled + (size_t)g * HDIM + lane * 2);
    float p[NOUT];
#pragma unroll
    for (int o = 0; o < NOUT; ++o)
        p[o] = v.x * Wlin[(size_t)(2 * lane) * NOUT + o] +
               v.y * Wlin[(size_t)(2 * lane + 1) * NOUT + o];
#pragma unroll
    for (int mask = 1; mask < 64; mask <<= 1)
#pragma unroll
        for (int o = 0; o < NOUT; ++o) p[o] += __shfl_xor(p[o], mask);
    if (lane == 0) {
        float lg[NOUT];
        float mx = -1e30f;
#pragma unroll
        for (int o = 0; o < NOUT; ++o) { lg[o] = p[o] + blin[o]; mx = fmaxf(mx, lg[o]); }
        float se = 0.f;
#pragma unroll
        for (int o = 0; o < NOUT; ++o) se += expf(lg[o] - mx);
        float lse = mx + logf(se);
#pragma unroll
        for (int o = 0; o < NOUT; ++o) out[g * NOUT + o] = lg[o] - lse;
    }
}

// ---------------- host ----------------

extern "C" void kernel_launch(void* const* d_in, const int* in_sizes, int n_in,
                              void* d_out, int out_size, void* d_ws, size_t ws_size,
                              hipStream_t stream) {
    const float* x0     = (const float*)d_in[0];
    const int*   edge   = (const int*)d_in[1];
    const int*   src    = edge;
    const int*   dst    = edge + N_EDGES;
    const float* lam    = (const float*)d_in[2];
    const int*   perm1  = (const int*)d_in[5];
    const int*   perm2  = (const int*)d_in[6];
    const float* W1_rel = (const float*)d_in[8];
    const float* b1_rel = (const float*)d_in[9];
    const float* W1_root= (const float*)d_in[10];
    const float* W2_rel = (const float*)d_in[11];
    const float* b2_rel = (const float*)d_in[12];
    const float* W2_root= (const float*)d_in[13];
    const float* W_lin  = (const float*)d_in[14];
    const float* b_lin  = (const float*)d_in[15];
    float* out = (float*)d_out;

    char* w = (char*)d_ws;
    size_t off = 0;
    auto alloc = [&](size_t bytes) -> void* {
        void* p = w + off;
        off = (off + bytes + 255) & ~(size_t)255;
        return p;
    };
    int* cnt       = (int*)alloc((size_t)N_NODES * 4);
    ushort_t* col2 = (ushort_t*)alloc((size_t)N_NODES * SLOT * 2);
    ushort_t* Abuf   = (ushort_t*)alloc((size_t)N_NODES * AK * 2);
    ushort_t* ybuf   = (ushort_t*)alloc((size_t)N_NODES * HDIM * 2);
    ushort_t* Wfrag1 = (ushort_t*)alloc(32768 * 2);
    ushort_t* Wfrag2 = (ushort_t*)alloc(32768 * 2);
    float* pooled    = (float*)alloc((size_t)NGRAPH * HDIM * 4);

    // block-histogram matrix aliases ybuf (10.24 MB <= 13.1 MB): ybuf is dead
    // until the layer-1 GEMM writes it, strictly after k_place completes.
    uint_t* bh = (uint_t*)ybuf;

    // prep (+ CSR count blocks first, overlapping the BW-bound cast blocks)
    k_prep<<<6920, 256, 0, stream>>>(x0, Abuf, W1_rel, W1_root, W2_rel, W2_root,
                                     Wfrag1, Wfrag2, pooled, dst, bh);
    k_prefix<<<HISTW / 32, 256, 0, stream>>>(bh, cnt);
    k_place<<<NBLK, 256, 0, stream>>>(src, dst, bh, col2);

    const int aggGrid  = N_NODES / 4;   // 12800
    const int gemmGrid = N_NODES / 32;  // 1600
    const int elGrid   = (N_NODES * HDIM / 4) / 256;  // 6400

    // layer 1
    k_aggregate<<<aggGrid, 256, 0, stream>>>(Abuf, cnt, col2);
    k_gemm256<0><<<gemmGrid, 256, 0, stream>>>(Abuf, Wfrag1, b1_rel, ybuf, pooled);
    k_mixup_toA<<<elGrid, 256, 0, stream>>>(ybuf, perm1, lam, Abuf);
    // layer 2
    k_aggregate<<<aggGrid, 256, 0, stream>>>(Abuf, cnt, col2);
    k_gemm256<0><<<gemmGrid, 256, 0, stream>>>(Abuf, Wfrag2, b2_rel, ybuf, pooled);
    k_mixup_toA<<<elGrid, 256, 0, stream>>>(ybuf, perm2, lam, Abuf);
    // layer 3 (mixup3 is a pooling no-op -> fused pool)
    k_aggregate<<<aggGrid, 256, 0, stream>>>(Abuf, cnt, col2);
    k_gemm256<1><<<gemmGrid, 256, 0, stream>>>(Abuf, Wfrag2, b2_rel, ybuf, pooled);

    // classifier + log_softmax
    k_final<<<NGRAPH, 64, 0, stream>>>(pooled, W_lin, b_lin, out);
}